// Round 12
// baseline (408.477 us; speedup 1.0000x reference)
//
#include <hip/hip_runtime.h>
#include <hip/hip_bf16.h>

#define D_MODEL 1024
#define NHEAD 16
#define D_HEAD 64
#define D_FF 4096
#define BATCH 2
#define SEQ 2048
#define M_TOK (BATCH * SEQ)   // 4096 rows
#define EPS 1e-5f
#define QKV_N 3072

using bf16 = __hip_bfloat16;
typedef __attribute__((ext_vector_type(8))) short short8;
typedef __attribute__((ext_vector_type(4))) short short4v;
typedef __attribute__((ext_vector_type(4))) float float4v;
typedef __attribute__((ext_vector_type(16))) float float16v;

__device__ __forceinline__ float b2f(unsigned short u) {
    union { unsigned int i; float f; } v; v.i = ((unsigned int)u) << 16; return v.f;
}
__device__ __forceinline__ unsigned short f2b(float f) {   // RNE f32->bf16
    union { float f; unsigned int u; } v; v.f = f;
    unsigned int r = v.u + 0x7FFFu + ((v.u >> 16) & 1u);
    return (unsigned short)(r >> 16);
}
__device__ __forceinline__ float loadAt(const void* p, size_t i, int f32) {
    if (f32) return ((const float*)p)[i];
    return b2f(((const unsigned short*)p)[i]);
}
// Async global->LDS, 16 bytes per lane. LDS dest = wave-uniform base + lane*16.
__device__ __forceinline__ void async16(const void* g, void* lds) {
    __builtin_amdgcn_global_load_lds(
        (const __attribute__((address_space(1))) unsigned int*)g,
        (__attribute__((address_space(3))) unsigned int*)lds, 16, 0, 0);
}
// Pack two f32 -> bf16x2 word (RNE), single instruction.
__device__ __forceinline__ unsigned int cvt_pk_bf16(float lo, float hi) {
    unsigned int r;
    asm("v_cvt_pk_bf16_f32 %0, %1, %2" : "=v"(r) : "v"(lo), "v"(hi));
    return r;
}
// Swap high 32 lanes of a with low 32 lanes of b (both registers modified).
__device__ __forceinline__ void pl32_swap(unsigned int& a, unsigned int& b) {
    asm("v_permlane32_swap_b32 %0, %1" : "+v"(a), "+v"(b));
}

// ---------------------------------------------------------------------------
__global__ void detect_kernel(const unsigned short* __restrict__ x, int* __restrict__ flag) {
    __shared__ int cnt;
    if (threadIdx.x == 0) cnt = 0;
    __syncthreads();
    int c = 0;
    for (int i = threadIdx.x; i < 8192; i += 256) {
        unsigned short u = x[i];
        int e = (u >> 7) & 0xFF;
        if (e >= 0xF0) c++;
    }
    atomicAdd(&cnt, c);
    __syncthreads();
    if (threadIdx.x == 0) { flag[0] = (cnt > 16) ? 1 : 0; flag[1] = 0; }
}

// ---------------------------------------------------------------------------
__global__ __launch_bounds__(256) void cast_bf16_kernel(
    const void* __restrict__ src, bf16* __restrict__ dst, int n,
    const int* __restrict__ flagp) {
    const int f32 = *flagp;
    int i0 = (blockIdx.x * 256 + threadIdx.x) * 8;
    if (i0 >= n) return;
    short8 v;
    if (f32) {
        const float* pf = (const float*)src + i0;
        float4v f0 = *(const float4v*)pf;
        float4v f1 = *(const float4v*)(pf + 4);
#pragma unroll
        for (int i = 0; i < 4; i++) { v[i] = (short)f2b(f0[i]); v[4 + i] = (short)f2b(f1[i]); }
    } else {
        v = *(const short8*)((const short*)src + i0);
    }
    *(short8*)((short*)dst + i0) = v;
}

// ---------------------------------------------------------------------------
__global__ __launch_bounds__(256) void cast3_bf16_kernel(
    const void* __restrict__ s0, const void* __restrict__ s1,
    const void* __restrict__ s2, bf16* __restrict__ dst,
    const int* __restrict__ flagp) {
    const int f32 = *flagp;
    int i0 = (blockIdx.x * 256 + threadIdx.x) * 8;
    const int part = i0 >> 20;
    const int off = i0 & ((1 << 20) - 1);
    const void* src = (part == 0) ? s0 : (part == 1) ? s1 : s2;
    short8 v;
    if (f32) {
        const float* pf = (const float*)src + off;
        float4v f0 = *(const float4v*)pf;
        float4v f1 = *(const float4v*)(pf + 4);
#pragma unroll
        for (int i = 0; i < 4; i++) { v[i] = (short)f2b(f0[i]); v[4 + i] = (short)f2b(f1[i]); }
    } else {
        v = *(const short8*)((const short*)src + off);
    }
    *(short8*)((short*)dst + i0) = v;
}

// ---------------------------------------------------------------------------
__global__ __launch_bounds__(256) void cast2_bf16_kernel(
    const void* __restrict__ s0, const void* __restrict__ s1,
    bf16* __restrict__ d0, bf16* __restrict__ d1,
    const int* __restrict__ flagp) {
    const int f32 = *flagp;
    int i0 = (blockIdx.x * 256 + threadIdx.x) * 8;
    const void* src; short* dst; int off;
    if (i0 < (1 << 20)) { src = s0; dst = (short*)d0; off = i0; }
    else                { src = s1; dst = (short*)d1; off = i0 - (1 << 20); }
    short8 v;
    if (f32) {
        const float* pf = (const float*)src + off;
        float4v f0 = *(const float4v*)pf;
        float4v f1 = *(const float4v*)(pf + 4);
#pragma unroll
        for (int i = 0; i < 4; i++) { v[i] = (short)f2b(f0[i]); v[4 + i] = (short)f2b(f1[i]); }
    } else {
        v = *(const short8*)((const short*)src + off);
    }
    *(short8*)(dst + off) = v;
}

// ---------------------------------------------------------------------------
__device__ __forceinline__ void stage8(const void* src, size_t off, int f32, short* dst) {
    short8 v;
    if (f32) {
        const float* pf = (const float*)src + off;
        float4v f0 = *(const float4v*)pf;
        float4v f1 = *(const float4v*)(pf + 4);
#pragma unroll
        for (int i = 0; i < 4; i++) { v[i] = (short)f2b(f0[i]); v[4 + i] = (short)f2b(f1[i]); }
    } else {
        v = *(const short8*)((const short*)src + off);
    }
    *(short8*)dst = v;
}

// ---------------------------------------------------------------------------
// MFMA GEMM v2 (R9-verified math): BK=64, 128B LDS rows, XOR chunk swizzle.
// MSWZ=true: 1D grid, XCD-partitioned M (T1-style bijective swizzle; R7:
// +18 us on Wo+FFN2 at 64^2). MF=1 (32-row tiles): doubles blocks/CU to 8
// (32 waves/CU = occupancy cap) for the latency-bound N=1024 GEMMs; wave
// coverage audited (A-staging wv*8+sRow covers 32 rows, compute wm*16+lrow).
// ---------------------------------------------------------------------------
template <int MF, int NF, bool RELU, bool BDYN, bool MSWZ>
__global__ __launch_bounds__(256) void gemm_mfma(
    const bf16* __restrict__ A, const void* __restrict__ B,
    const void* __restrict__ bias0, const void* __restrict__ bias1,
    const void* __restrict__ bias2, int nb1, int nb2,
    bf16* __restrict__ C, int N, int K, const int* __restrict__ inFlagp) {
    static_assert(!BDYN || NF == 2, "BDYN staging layout assumes BN=64");
    constexpr int BM = 32 * MF, BN = 32 * NF;
    __shared__ short As[BM * 64];
    __shared__ short Bs[BN * 64];
    const int tid = threadIdx.x;
    const int lane = tid & 63;
    const int wv = tid >> 6;
    const int wm = wv & 1, wn = wv >> 1;
    const int quad = lane >> 4, lrow = lane & 15;
    int rowM, rowN;
    if (MSWZ) {
        // 1D grid: xcd = orig%8 (hardware round-robin); XCD k owns M-tiles
        // [k*mpx, (k+1)*mpx) x all nt N-tiles, N-outer within the XCD.
        const int nt = N / BN;
        const int mpx = (gridDim.x / 8) / nt;       // M-tiles per XCD
        const int orig = blockIdx.x;
        const int xcd = orig & 7, idx = orig >> 3;
        rowN = (idx / mpx) * BN;
        rowM = (xcd * mpx + (idx % mpx)) * BM;
    } else {
        rowM = blockIdx.y * BM;
        rowN = blockIdx.x * BN;
    }
    const int inf = *inFlagp;

    float4v acc[MF][NF];
    const float4v zero = {0.f, 0.f, 0.f, 0.f};
#pragma unroll
    for (int i = 0; i < MF; i++)
#pragma unroll
        for (int j = 0; j < NF; j++) acc[i][j] = zero;

    const int sRow = lane >> 3;
    const int gChunk = (lane & 7) ^ sRow;

    for (int k0 = 0; k0 < K; k0 += 64) {
        if (MF >= 2) {
#pragma unroll
            for (int rd = 0; rd < MF; rd++) {
                const short* gp = (const short*)A +
                    (size_t)(rowM + rd * 32 + wv * 8 + sRow) * K + k0 + gChunk * 8;
                async16(gp, &As[rd * 2048 + wv * 512]);
            }
        } else {
            // MF==1: 4 waves cover the 32 A-rows (wv*8 + sRow)
            const short* gp = (const short*)A +
                (size_t)(rowM + wv * 8 + sRow) * K + k0 + gChunk * 8;
            async16(gp, &As[wv * 512]);
        }
        if (!BDYN) {
#pragma unroll
            for (int rd = 0; rd < NF; rd++) {
                const short* gp = (const short*)B +
                    (size_t)(rowN + rd * 32 + wv * 8 + sRow) * K + k0 + gChunk * 8;
                async16(gp, &Bs[rd * 2048 + wv * 512]);
            }
        } else {
            const int brow = tid >> 2;
            const int c0 = (tid & 3) * 2;
#pragma unroll
            for (int cc = 0; cc < 2; cc++) {
                int slot = c0 + cc;
                int g = slot ^ (brow & 7);
                stage8(B, (size_t)(rowN + brow) * K + k0 + g * 8, inf,
                       &Bs[brow * 64 + slot * 8]);
            }
        }
        __syncthreads();
#pragma unroll
        for (int ks = 0; ks < 2; ks++) {
            short8 a_frag[MF], b_frag[NF];
#pragma unroll
            for (int i = 0; i < MF; i++) {
                const int row = wm * MF * 16 + i * 16 + lrow;
                const int slot = (ks * 4 + quad) ^ (row & 7);
                a_frag[i] = *(const short8*)&As[row * 64 + slot * 8];
            }
#pragma unroll
            for (int j = 0; j < NF; j++) {
                const int row = wn * NF * 16 + j * 16 + lrow;
                const int slot = (ks * 4 + quad) ^ (row & 7);
                b_frag[j] = *(const short8*)&Bs[row * 64 + slot * 8];
            }
#pragma unroll
            for (int i = 0; i < MF; i++)
#pragma unroll
                for (int j = 0; j < NF; j++)
                    acc[i][j] = __builtin_amdgcn_mfma_f32_16x16x32_bf16(
                        a_frag[i], b_frag[j], acc[i][j], 0, 0, 0);
        }
        __syncthreads();
    }

    const int mB = rowM + wm * MF * 16, nB = rowN + wn * NF * 16;
    unsigned short* Cu = (unsigned short*)C;
#pragma unroll
    for (int j = 0; j < NF; j++) {
        const int col = nB + j * 16 + lrow;
        float bv;
        if (col < nb1)      bv = loadAt(bias0, col, inf);
        else if (col < nb2) bv = loadAt(bias1, col - nb1, inf);
        else                bv = loadAt(bias2, col - nb2, inf);
#pragma unroll
        for (int i = 0; i < MF; i++) {
#pragma unroll
            for (int r = 0; r < 4; r++) {
                const int rowg = mB + i * 16 + quad * 4 + r;
                float vv = acc[i][j][r] + bv;
                if (RELU) vv = fmaxf(vv, 0.0f);
                Cu[(size_t)rowg * N + col] = f2b(vv);
            }
        }
    }
}

// ---------------------------------------------------------------------------
// MFMA flash attention v13 (R11-verified, 79.8 us): V-pack/write after PV,
// zconst C-in, v_perm byte-merge, lsum-via-MFMA, XCD head-affinity
// (FETCH 69.7 -> 12.4 MB verified), swapped QK^T + in-register P, setprio.
// ---------------------------------------------------------------------------
#define FSTRIDE 66
__global__ __launch_bounds__(256) void flash_attn_kernel(
    const bf16* __restrict__ Qb, const bf16* __restrict__ Kb,
    const bf16* __restrict__ Vb, bf16* __restrict__ O) {
    const int orig = blockIdx.x;
    const int xcd = orig & 7;           // hardware XCD round-robin
    const int idx = orig >> 3;          // 0..63 within XCD
    const int bh  = xcd * 4 + (idx >> 4);   // 4 (b,h) pairs per XCD
    const int qt  = idx & 15;           // S/128 = 16 q-tiles
    const int h  = bh & 15;
    const int b  = bh >> 4;
    const int q0 = qt * 128;
    const int tid = threadIdx.x;
    const int lane = tid & 63;
    const int wv = tid >> 6;            // 0..3
    const int half = lane >> 5;         // 0/1
    const int l31 = lane & 31;

    __shared__ short Ab[128 * FSTRIDE];     // Q staging
    __shared__ short Ks[2][64 * 64];        // async-staged, XOR-swizzled, dbuf
    __shared__ short Vt[2][64 * FSTRIDE];   // V^T, dbuf

    const size_t headOff = (size_t)h * D_HEAD;
    const float SCF = 0.18033688f;      // 0.125 * log2(e), folded into Q

    // Stage Q (128 rows x 64 shorts), scaled by SCF. 2 threads per row.
    {
        int r = tid >> 1, c0 = (tid & 1) * 32;
        const short* src = (const short*)Qb + (size_t)(b * SEQ + q0 + r) * QKV_N + headOff + c0;
#pragma unroll
        for (int ch = 0; ch < 4; ch++) {
            short8 v = *(const short8*)(src + ch * 8);
            short8 o;
#pragma unroll
            for (int e = 0; e < 8; e++)
                o[e] = (short)f2b(b2f((unsigned short)v[e]) * SCF);
            *(short8*)&Ab[r * FSTRIDE + c0 + ch * 8] = o;
        }
    }

    const int sRow = lane >> 3;             // 0..7
    const int gChunk = (lane & 7) ^ sRow;   // global chunk for swizzled slot
    const int vjp = (tid & 31) * 2;         // V: 2 j's per thread
    const int vd0 = (tid >> 5) * 8;         // V: 8 d's per thread

    // Prologue: prefetch tile 0 (K async -> Ks[0], V -> regs)
#pragma unroll
    for (int rd = 0; rd < 2; rd++) {
        const short* gp = (const short*)Kb +
            (size_t)(b * SEQ + rd * 32 + wv * 8 + sRow) * QKV_N + headOff + gChunk * 8;
        async16(gp, &Ks[0][(rd * 32 + wv * 8) * 64]);
    }
    short8 v0, v1;
    {
        const short* s0 = (const short*)Vb + (size_t)(b * SEQ + vjp) * QKV_N + headOff + vd0;
        v0 = *(const short8*)s0;
        v1 = *(const short8*)(s0 + QKV_N);
    }
    __syncthreads();   // Q visible; K(0) landed; V(0) regs ready

    short8 a_q[4];     // Q fragment (B-operand of swapped QK^T)
#pragma unroll
    for (int ks = 0; ks < 4; ks++)
        a_q[ks] = *(const short8*)&Ab[(wv * 32 + l31) * FSTRIDE + ks * 16 + half * 8];

    // Write V(0) -> Vt[0] via v_perm byte-merge
    {
        union { short8 s; unsigned int w[4]; } U0, U1;
        U0.s = v0; U1.s = v1;
#pragma unroll
        for (int w = 0; w < 4; w++) {
            unsigned int we = __builtin_amdgcn_perm(U1.w[w], U0.w[w], 0x05040100u);
            unsigned int wo = __builtin_amdgcn_perm(U1.w[w], U0.w[w], 0x07060302u);
            *(unsigned int*)&Vt[0][(vd0 + 2 * w) * FSTRIDE + vjp] = we;
            *(unsigned int*)&Vt[0][(vd0 + 2 * w + 1) * FSTRIDE + vjp] = wo;
        }
    }
    __syncthreads();   // Vt[0] visible

    short8 vone;       // bf16 1.0 x8 (B-operand for the l-sum MFMA)
#pragma unroll
    for (int e = 0; e < 8; e++) vone[e] = (short)0x3F80;
    float16v zconst;   // persistent zero C-in for first QK MFMA (no re-init)
#pragma unroll
    for (int i = 0; i < 16; i++) zconst[i] = 0.f;

    float16v o_acc[2], l_acc;
#pragma unroll
    for (int i = 0; i < 16; i++) { o_acc[0][i] = 0.f; o_acc[1][i] = 0.f; l_acc[i] = 0.f; }

    int cb = 0;
    for (int t = 0; t < SEQ / 64; t++) {
        // Prefetch tile t+1 (clamped to last tile: harmless re-stage, no OOB)
        const int jn = (t < SEQ / 64 - 1) ? (t + 1) * 64 : t * 64;
#pragma unroll
        for (int rd = 0; rd < 2; rd++) {
            const short* gp = (const short*)Kb +
                (size_t)(b * SEQ + jn + rd * 32 + wv * 8 + sRow) * QKV_N + headOff + gChunk * 8;
            async16(gp, &Ks[cb ^ 1][(rd * 32 + wv * 8) * 64]);
        }
        {
            const short* s0 = (const short*)Vb + (size_t)(b * SEQ + jn + vjp) * QKV_N + headOff + vd0;
            v0 = *(const short8*)s0;
            v1 = *(const short8*)(s0 + QKV_N);
        }

        // Swapped QK^T: A = K rows (j), B = Q rows (q). C: row=j, col=q=l31.
        // First ks uses zconst as C-in (no 32-mov zero-init).
        float16v s_acc[2];
        __builtin_amdgcn_s_setprio(1);
#pragma unroll
        for (int jb = 0; jb < 2; jb++) {
            const int row = jb * 32 + l31;
            const int slot = half ^ (l31 & 7);   // ks=0
            short8 kfr = *(const short8*)&Ks[cb][row * 64 + slot * 8];
            s_acc[jb] = __builtin_amdgcn_mfma_f32_32x32x16_bf16(kfr, a_q[0], zconst, 0, 0, 0);
        }
#pragma unroll
        for (int ks = 1; ks < 4; ks++)
#pragma unroll
            for (int jb = 0; jb < 2; jb++) {
                const int row = jb * 32 + l31;
                const int slot = (ks * 2 + half) ^ (l31 & 7);
                short8 kfr = *(const short8*)&Ks[cb][row * 64 + slot * 8];
                s_acc[jb] = __builtin_amdgcn_mfma_f32_32x32x16_bf16(kfr, a_q[ks], s_acc[jb], 0, 0, 0);
            }
        __builtin_amdgcn_s_setprio(0);

        // p = exp2(s) in-register
#pragma unroll
        for (int jb = 0; jb < 2; jb++)
#pragma unroll
            for (int reg = 0; reg < 16; reg++)
                s_acc[jb][reg] = exp2f(s_acc[jb][reg]);

        // T12: build PV A-fragments in-register (cvt_pk + permlane32_swap)
        short8 pa[4];
#pragma unroll
        for (int jb = 0; jb < 2; jb++)
#pragma unroll
            for (int c = 0; c < 2; c++) {
                unsigned int a0 = cvt_pk_bf16(s_acc[jb][8 * c + 0], s_acc[jb][8 * c + 1]);
                unsigned int a1 = cvt_pk_bf16(s_acc[jb][8 * c + 2], s_acc[jb][8 * c + 3]);
                unsigned int b0 = cvt_pk_bf16(s_acc[jb][8 * c + 4], s_acc[jb][8 * c + 5]);
                unsigned int b1 = cvt_pk_bf16(s_acc[jb][8 * c + 6], s_acc[jb][8 * c + 7]);
                pl32_swap(a0, b0);
                pl32_swap(a1, b1);
                union { unsigned int w[4]; short8 s; } u;
                u.w[0] = a0; u.w[1] = a1; u.w[2] = b0; u.w[3] = b1;
                pa[jb * 2 + c] = u.s;
            }

        // PV: A = pa (in regs), B = Vt[cb] (2 d-blocks x 4 k-chunks).
        // l_acc: denominator via mfma(pa, ones) on the MFMA pipe.
        __builtin_amdgcn_s_setprio(1);
#pragma unroll
        for (int ks = 0; ks < 4; ks++) {
#pragma unroll
            for (int db = 0; db < 2; db++) {
                short8 vbf = *(const short8*)&Vt[cb][(db * 32 + l31) * FSTRIDE + ks * 16 + half * 8];
                o_acc[db] = __builtin_amdgcn_mfma_f32_32x32x16_bf16(pa[ks], vbf, o_acc[db], 0, 0, 0);
            }
            l_acc = __builtin_amdgcn_mfma_f32_32x32x16_bf16(pa[ks], vone, l_acc, 0, 0, 0);
        }
        __builtin_amdgcn_s_setprio(0);

        // Write V(t+1) -> Vt[cb^1] after PV (R9/R11 placement): PV's
        // ds_reads stay ahead of these ds_writes on the LDS pipe.
        {
            union { short8 s; unsigned int w[4]; } U0, U1;
            U0.s = v0; U1.s = v1;
#pragma unroll
            for (int w = 0; w < 4; w++) {
                unsigned int we = __builtin_amdgcn_perm(U1.w[w], U0.w[w], 0x05040100u);
                unsigned int wo = __builtin_amdgcn_perm(U1.w[w], U0.w[w], 0x07060302u);
                *(unsigned int*)&Vt[cb ^ 1][(vd0 + 2 * w) * FSTRIDE + vjp] = we;
                *(unsigned int*)&Vt[cb ^ 1][(vd0 + 2 * w + 1) * FSTRIDE + vjp] = wo;
            }
        }

        __syncthreads();   // drains: K(t+1) in Ks[cb^1], Vt[cb^1] visible,
                           // all waves done reading Ks[cb]/Vt[cb]
        cb ^= 1;
    }

    // l_acc[reg] = l for q-row rowC (identical in every lane): no shuffles.
    unsigned short* Ou = (unsigned short*)O;
#pragma unroll
    for (int reg = 0; reg < 16; reg++) {
        const int rowC = (reg & 3) + 8 * (reg >> 2) + 4 * half;
        const float invl = 1.0f / l_acc[reg];
        const int rowg = b * SEQ + q0 + wv * 32 + rowC;
#pragma unroll
        for (int db = 0; db < 2; db++)
            Ou[(size_t)rowg * D_MODEL + headOff + db * 32 + l31] =
                f2b(o_acc[db][reg] * invl);
    }
}

// ---------------------------------------------------------------------------
// out = LayerNorm(X + R) * g + be — one block per row of 1024, vectorized x4.
// ---------------------------------------------------------------------------
template <bool OUT_F32>
__global__ __launch_bounds__(256) void add_ln_kernel(
    const void* __restrict__ X, const bf16* __restrict__ R,
    const void* __restrict__ g, const void* __restrict__ be,
    void* __restrict__ Y,
    const int* __restrict__ xFlagp, const int* __restrict__ wFlagp) {
    const int xf = *xFlagp;
    const int wf = *wFlagp;
    const int row = blockIdx.x;
    const size_t base = (size_t)row * D_MODEL;
    const int tid = threadIdx.x;
    const int i0 = tid * 4;
    __shared__ float red[256];
    float v[4];
    if (xf) {
        float4v xv = *(const float4v*)((const float*)X + base + i0);
        short4v rv = *(const short4v*)((const short*)R + base + i0);
#pragma unroll
        for (int i = 0; i < 4; i++) v[i] = xv[i] + b2f((unsigned short)rv[i]);
    } else {
        short4v xv = *(const short4v*)((const short*)X + base + i0);
        short4v rv = *(const short4v*)((const short*)R + base + i0);
#pragma unroll
        for (int i = 0; i < 4; i++) v[i] = b2f((unsigned short)xv[i]) + b2f((unsigned short)rv[i]);
    }
    float s = v[0] + v[1] + v[2] + v[3];
    red[tid] = s; __syncthreads();
    for (int s2 = 128; s2 > 0; s2 >>= 1) {
        if (tid < s2) red[tid] += red[tid + s2];
        __syncthreads();
    }
    float mu = red[0] * (1.0f / D_MODEL);
    __syncthreads();
    float s2v = 0.f;
#pragma unroll
    for (int i = 0; i < 4; i++) { float dd = v[i] - mu; s2v += dd * dd; }
    red[tid] = s2v; __syncthreads();
    for (int s2 = 128; s2 > 0; s2 >>= 1) {
        if (tid < s2) red[tid] += red[tid + s2];
        __syncthreads();
    }
    float rstd = rsqrtf(red[0] * (1.0f / D_MODEL) + EPS);
    float gv[4], bv[4];
    if (wf) {
        float4v gg = *(const float4v*)((const float*)g + i0);
        float4v bb = *(const float4v*)((const float*)be + i0);
#pragma unroll
        for (int i = 0; i < 4; i++) { gv[i] = gg[i]; bv[i] = bb[i]; }
    } else {
        short4v gg = *(const short4v*)((const short*)g + i0);
        short4v bb = *(const short4v*)((const short*)be + i0);
#pragma unroll
        for (int i = 0; i < 4; i++) { gv[i] = b2f((unsigned short)gg[i]); bv[i] = b2f((unsigned short)bb[i]); }
    }
    if (OUT_F32) {
        float4v o;
#pragma unroll
        for (int i = 0; i < 4; i++) o[i] = (v[i] - mu) * rstd * gv[i] + bv[i];
        *(float4v*)((float*)Y + base + i0) = o;
    } else {
        short4v o;
#pragma unroll
        for (int i = 0; i < 4; i++) o[i] = (short)f2b((v[i] - mu) * rstd * gv[i] + bv[i]);
        *(short4v*)((short*)Y + base + i0) = o;
    }
}

// ---------------------------------------------------------------------------
extern "C" void kernel_launch(void* const* d_in, const int* in_sizes, int n_in,
                              void* d_out, int out_size, void* d_ws, size_t ws_size,
                              hipStream_t stream) {
    const void* x  = d_in[0];
    const void* Wq = d_in[1];  const void* bq = d_in[2];
    const void* Wk = d_in[3];  const void* bk = d_in[4];
    const void* Wv = d_in[5];  const void* bv = d_in[6];
    const void* Wo = d_in[7];  const void* bo = d_in[8];
    const void* W1 = d_in[9];  const void* b1 = d_in[10];
    const void* W2 = d_in[11]; const void* b2 = d_in[12];
    const void* g1 = d_in[13]; const void* be1 = d_in[14];
    const void* g2 = d_in[15]; const void* be2 = d_in[16];

    char* ws = (char*)d_ws;
    const size_t MB = 1024 * 1024;
    // Proven R9-R12 choreography (48 MB core):
    bf16* xb     = (bf16*)(ws + 0 * MB);
    bf16* wqkvb  = (bf16*)(ws + 8 * MB);
    bf16* wob    = (bf16*)(ws + 14 * MB);
    bf16* qkv    = (bf16*)(ws + 16 * MB);
    bf16* concat = (bf16*)(ws + 40 * MB);
    bf16* w1b    = (bf16*)(ws + 0 * MB);
    bf16* proj   = (bf16*)(ws + 16 * MB);
    bf16* hb     = (bf16*)(ws + 8 * MB);
    bf16* ffn1   = (bf16*)(ws + 16 * MB);
    bf16* ffn2   = (bf16*)(ws + 0 * MB);
    const bool castW2 = (ws_size >= 56 * MB + 8);
    bf16* w2b    = (bf16*)(ws + 48 * MB);
    int*  flag   = (int*)(ws + (castW2 ? 56 * MB : 48 * MB));

    const int* fIn = flag;
    const int* fBf = flag + 1;

    dim3 blk(256);

    detect_kernel<<<dim3(1), blk, 0, stream>>>((const unsigned short*)x, flag);
    cast_bf16_kernel<<<dim3((M_TOK * D_MODEL / 8 + 255) / 256), blk, 0, stream>>>(x, xb, M_TOK * D_MODEL, fIn);
    cast3_bf16_kernel<<<dim3(3 * D_MODEL * D_MODEL / 8 / 256), blk, 0, stream>>>(Wq, Wk, Wv, wqkvb, fIn);
    if (castW2)
        cast_bf16_kernel<<<dim3((D_FF * D_MODEL / 8 + 255) / 256), blk, 0, stream>>>(W2, w2b, D_FF * D_MODEL, fIn);
    // Fused QKV projection: 128x128 tiles, 768 blocks, XCD-partitioned M
    gemm_mfma<4, 4, false, false, true><<<dim3((QKV_N / 128) * (M_TOK / 128)), blk, 0, stream>>>(
        xb, wqkvb, bq, bk, bv, 1024, 2048, qkv, QKV_N, D_MODEL, fIn);
    // Wo + W1 casts in one launch (xb dead now)
    cast2_bf16_kernel<<<dim3(5 * D_MODEL * D_MODEL / 8 / 256), blk, 0, stream>>>(Wo, W1, wob, w1b, fIn);
    // Flash attention v13: 512 blocks x 256 threads (R11-verified, 79.8 us)
    flash_attn_kernel<<<dim3(BATCH * NHEAD * (SEQ / 128)), dim3(256), 0, stream>>>(
        qkv, qkv + D_MODEL, qkv + 2 * D_MODEL, concat);
    // Output projection: 32x64 tiles -> 2048 blocks = 8/CU (32 waves/CU),
    // XCD-partitioned M (nt=16, mpx=16)
    gemm_mfma<1, 2, false, false, true><<<dim3((D_MODEL / 64) * (M_TOK / 32)), blk, 0, stream>>>(
        concat, wob, bo, bo, bo, D_MODEL, D_MODEL, proj, D_MODEL, D_MODEL, fIn);
    add_ln_kernel<false><<<dim3(M_TOK), blk, 0, stream>>>(x, proj, g1, be1, hb, fIn, fIn);
    // FFN1: 128x128 tiles, ReLU, non-swizzled (R10 config; R11's MSWZ at
    // 128^2 coincided with +10 us non-flash -- reverted)
    gemm_mfma<4, 4, true, false, false><<<dim3(D_FF / 128, M_TOK / 128), blk, 0, stream>>>(
        hb, w1b, b1, b1, b1, D_FF, D_FF, ffn1, D_FF, D_MODEL, fIn);
    // FFN2: 32x64 tiles -> 2048 blocks = 8/CU, XCD-partitioned M
    if (castW2)
        gemm_mfma<1, 2, false, false, true><<<dim3((D_MODEL / 64) * (M_TOK / 32)), blk, 0, stream>>>(
            ffn1, w2b, b2, b2, b2, D_MODEL, D_MODEL, ffn2, D_MODEL, D_FF, fIn);
    else
        gemm_mfma<1, 2, false, true, true><<<dim3((D_MODEL / 64) * (M_TOK / 32)), blk, 0, stream>>>(
            ffn1, W2, b2, b2, b2, D_MODEL, D_MODEL, ffn2, D_MODEL, D_FF, fIn);
    add_ln_kernel<true><<<dim3(M_TOK), blk, 0, stream>>>(hb, ffn2, g2, be2, d_out, fBf, fIn);
}

// Round 13
// 375.080 us; speedup vs baseline: 1.0890x; 1.0890x over previous
//
#include <hip/hip_runtime.h>
#include <hip/hip_bf16.h>

#define D_MODEL 1024
#define NHEAD 16
#define D_HEAD 64
#define D_FF 4096
#define BATCH 2
#define SEQ 2048
#define M_TOK (BATCH * SEQ)   // 4096 rows
#define EPS 1e-5f
#define QKV_N 3072

using bf16 = __hip_bfloat16;
typedef __attribute__((ext_vector_type(8))) short short8;
typedef __attribute__((ext_vector_type(4))) short short4v;
typedef __attribute__((ext_vector_type(4))) float float4v;
typedef __attribute__((ext_vector_type(16))) float float16v;

__device__ __forceinline__ float b2f(unsigned short u) {
    union { unsigned int i; float f; } v; v.i = ((unsigned int)u) << 16; return v.f;
}
__device__ __forceinline__ unsigned short f2b(float f) {   // RNE f32->bf16
    union { float f; unsigned int u; } v; v.f = f;
    unsigned int r = v.u + 0x7FFFu + ((v.u >> 16) & 1u);
    return (unsigned short)(r >> 16);
}
__device__ __forceinline__ float loadAt(const void* p, size_t i, int f32) {
    if (f32) return ((const float*)p)[i];
    return b2f(((const unsigned short*)p)[i]);
}
// Async global->LDS, 16 bytes per lane. LDS dest = wave-uniform base + lane*16.
__device__ __forceinline__ void async16(const void* g, void* lds) {
    __builtin_amdgcn_global_load_lds(
        (const __attribute__((address_space(1))) unsigned int*)g,
        (__attribute__((address_space(3))) unsigned int*)lds, 16, 0, 0);
}
// Pack two f32 -> bf16x2 word (RNE), single instruction.
__device__ __forceinline__ unsigned int cvt_pk_bf16(float lo, float hi) {
    unsigned int r;
    asm("v_cvt_pk_bf16_f32 %0, %1, %2" : "=v"(r) : "v"(lo), "v"(hi));
    return r;
}
// Swap high 32 lanes of a with low 32 lanes of b (both registers modified).
__device__ __forceinline__ void pl32_swap(unsigned int& a, unsigned int& b) {
    asm("v_permlane32_swap_b32 %0, %1" : "+v"(a), "+v"(b));
}

// ---------------------------------------------------------------------------
__global__ void detect_kernel(const unsigned short* __restrict__ x, int* __restrict__ flag) {
    __shared__ int cnt;
    if (threadIdx.x == 0) cnt = 0;
    __syncthreads();
    int c = 0;
    for (int i = threadIdx.x; i < 8192; i += 256) {
        unsigned short u = x[i];
        int e = (u >> 7) & 0xFF;
        if (e >= 0xF0) c++;
    }
    atomicAdd(&cnt, c);
    __syncthreads();
    if (threadIdx.x == 0) { flag[0] = (cnt > 16) ? 1 : 0; flag[1] = 0; }
}

// ---------------------------------------------------------------------------
__global__ __launch_bounds__(256) void cast_bf16_kernel(
    const void* __restrict__ src, bf16* __restrict__ dst, int n,
    const int* __restrict__ flagp) {
    const int f32 = *flagp;
    int i0 = (blockIdx.x * 256 + threadIdx.x) * 8;
    if (i0 >= n) return;
    short8 v;
    if (f32) {
        const float* pf = (const float*)src + i0;
        float4v f0 = *(const float4v*)pf;
        float4v f1 = *(const float4v*)(pf + 4);
#pragma unroll
        for (int i = 0; i < 4; i++) { v[i] = (short)f2b(f0[i]); v[4 + i] = (short)f2b(f1[i]); }
    } else {
        v = *(const short8*)((const short*)src + i0);
    }
    *(short8*)((short*)dst + i0) = v;
}

// ---------------------------------------------------------------------------
__global__ __launch_bounds__(256) void cast3_bf16_kernel(
    const void* __restrict__ s0, const void* __restrict__ s1,
    const void* __restrict__ s2, bf16* __restrict__ dst,
    const int* __restrict__ flagp) {
    const int f32 = *flagp;
    int i0 = (blockIdx.x * 256 + threadIdx.x) * 8;
    const int part = i0 >> 20;
    const int off = i0 & ((1 << 20) - 1);
    const void* src = (part == 0) ? s0 : (part == 1) ? s1 : s2;
    short8 v;
    if (f32) {
        const float* pf = (const float*)src + off;
        float4v f0 = *(const float4v*)pf;
        float4v f1 = *(const float4v*)(pf + 4);
#pragma unroll
        for (int i = 0; i < 4; i++) { v[i] = (short)f2b(f0[i]); v[4 + i] = (short)f2b(f1[i]); }
    } else {
        v = *(const short8*)((const short*)src + off);
    }
    *(short8*)((short*)dst + i0) = v;
}

// ---------------------------------------------------------------------------
__global__ __launch_bounds__(256) void cast2_bf16_kernel(
    const void* __restrict__ s0, const void* __restrict__ s1,
    bf16* __restrict__ d0, bf16* __restrict__ d1,
    const int* __restrict__ flagp) {
    const int f32 = *flagp;
    int i0 = (blockIdx.x * 256 + threadIdx.x) * 8;
    const void* src; short* dst; int off;
    if (i0 < (1 << 20)) { src = s0; dst = (short*)d0; off = i0; }
    else                { src = s1; dst = (short*)d1; off = i0 - (1 << 20); }
    short8 v;
    if (f32) {
        const float* pf = (const float*)src + off;
        float4v f0 = *(const float4v*)pf;
        float4v f1 = *(const float4v*)(pf + 4);
#pragma unroll
        for (int i = 0; i < 4; i++) { v[i] = (short)f2b(f0[i]); v[4 + i] = (short)f2b(f1[i]); }
    } else {
        v = *(const short8*)((const short*)src + off);
    }
    *(short8*)(dst + off) = v;
}

// ---------------------------------------------------------------------------
__device__ __forceinline__ void stage8(const void* src, size_t off, int f32, short* dst) {
    short8 v;
    if (f32) {
        const float* pf = (const float*)src + off;
        float4v f0 = *(const float4v*)pf;
        float4v f1 = *(const float4v*)(pf + 4);
#pragma unroll
        for (int i = 0; i < 4; i++) { v[i] = (short)f2b(f0[i]); v[4 + i] = (short)f2b(f1[i]); }
    } else {
        v = *(const short8*)((const short*)src + off);
    }
    *(short8*)dst = v;
}

// ---------------------------------------------------------------------------
// MFMA GEMM v2 (R9-verified math): BK=64, 128B LDS rows, XOR chunk swizzle.
// MSWZ=true: 1D grid, XCD-partitioned M (T1-style bijective swizzle). R7
// established +18 us on Wo+FFN2 at 64^2; R11/R12 established 64^2 <2,2> as
// the saddle point (tile-up/split-K/pipeline/tile-down all regress).
// ---------------------------------------------------------------------------
template <int MF, int NF, bool RELU, bool BDYN, bool MSWZ>
__global__ __launch_bounds__(256) void gemm_mfma(
    const bf16* __restrict__ A, const void* __restrict__ B,
    const void* __restrict__ bias0, const void* __restrict__ bias1,
    const void* __restrict__ bias2, int nb1, int nb2,
    bf16* __restrict__ C, int N, int K, const int* __restrict__ inFlagp) {
    static_assert(!BDYN || NF == 2, "BDYN staging layout assumes BN=64");
    constexpr int BM = 32 * MF, BN = 32 * NF;
    __shared__ short As[BM * 64];
    __shared__ short Bs[BN * 64];
    const int tid = threadIdx.x;
    const int lane = tid & 63;
    const int wv = tid >> 6;
    const int wm = wv & 1, wn = wv >> 1;
    const int quad = lane >> 4, lrow = lane & 15;
    int rowM, rowN;
    if (MSWZ) {
        // 1D grid: xcd = orig%8 (hardware round-robin); XCD k owns M-tiles
        // [k*mpx, (k+1)*mpx) x all nt N-tiles, N-outer within the XCD.
        const int nt = N / BN;
        const int mpx = (gridDim.x / 8) / nt;       // M-tiles per XCD
        const int orig = blockIdx.x;
        const int xcd = orig & 7, idx = orig >> 3;
        rowN = (idx / mpx) * BN;
        rowM = (xcd * mpx + (idx % mpx)) * BM;
    } else {
        rowM = blockIdx.y * BM;
        rowN = blockIdx.x * BN;
    }
    const int inf = *inFlagp;

    float4v acc[MF][NF];
    const float4v zero = {0.f, 0.f, 0.f, 0.f};
#pragma unroll
    for (int i = 0; i < MF; i++)
#pragma unroll
        for (int j = 0; j < NF; j++) acc[i][j] = zero;

    const int sRow = lane >> 3;
    const int gChunk = (lane & 7) ^ sRow;

    for (int k0 = 0; k0 < K; k0 += 64) {
#pragma unroll
        for (int rd = 0; rd < MF; rd++) {
            const short* gp = (const short*)A +
                (size_t)(rowM + rd * 32 + wv * 8 + sRow) * K + k0 + gChunk * 8;
            async16(gp, &As[rd * 2048 + wv * 512]);
        }
        if (!BDYN) {
#pragma unroll
            for (int rd = 0; rd < NF; rd++) {
                const short* gp = (const short*)B +
                    (size_t)(rowN + rd * 32 + wv * 8 + sRow) * K + k0 + gChunk * 8;
                async16(gp, &Bs[rd * 2048 + wv * 512]);
            }
        } else {
            const int brow = tid >> 2;
            const int c0 = (tid & 3) * 2;
#pragma unroll
            for (int cc = 0; cc < 2; cc++) {
                int slot = c0 + cc;
                int g = slot ^ (brow & 7);
                stage8(B, (size_t)(rowN + brow) * K + k0 + g * 8, inf,
                       &Bs[brow * 64 + slot * 8]);
            }
        }
        __syncthreads();
#pragma unroll
        for (int ks = 0; ks < 2; ks++) {
            short8 a_frag[MF], b_frag[NF];
#pragma unroll
            for (int i = 0; i < MF; i++) {
                const int row = wm * MF * 16 + i * 16 + lrow;
                const int slot = (ks * 4 + quad) ^ (row & 7);
                a_frag[i] = *(const short8*)&As[row * 64 + slot * 8];
            }
#pragma unroll
            for (int j = 0; j < NF; j++) {
                const int row = wn * NF * 16 + j * 16 + lrow;
                const int slot = (ks * 4 + quad) ^ (row & 7);
                b_frag[j] = *(const short8*)&Bs[row * 64 + slot * 8];
            }
#pragma unroll
            for (int i = 0; i < MF; i++)
#pragma unroll
                for (int j = 0; j < NF; j++)
                    acc[i][j] = __builtin_amdgcn_mfma_f32_16x16x32_bf16(
                        a_frag[i], b_frag[j], acc[i][j], 0, 0, 0);
        }
        __syncthreads();
    }

    const int mB = rowM + wm * MF * 16, nB = rowN + wn * NF * 16;
    unsigned short* Cu = (unsigned short*)C;
#pragma unroll
    for (int j = 0; j < NF; j++) {
        const int col = nB + j * 16 + lrow;
        float bv;
        if (col < nb1)      bv = loadAt(bias0, col, inf);
        else if (col < nb2) bv = loadAt(bias1, col - nb1, inf);
        else                bv = loadAt(bias2, col - nb2, inf);
#pragma unroll
        for (int i = 0; i < MF; i++) {
#pragma unroll
            for (int r = 0; r < 4; r++) {
                const int rowg = mB + i * 16 + quad * 4 + r;
                float vv = acc[i][j][r] + bv;
                if (RELU) vv = fmaxf(vv, 0.0f);
                Cu[(size_t)rowg * N + col] = f2b(vv);
            }
        }
    }
}

// ---------------------------------------------------------------------------
// MFMA flash attention v13 (R11/R12-verified, 79.8-80.4 us): V-pack/write
// after PV, zconst C-in, v_perm byte-merge, lsum-via-MFMA, XCD head-affinity
// (FETCH 69.7 -> 12.4 MB verified), swapped QK^T + in-register P, setprio.
// ---------------------------------------------------------------------------
#define FSTRIDE 66
__global__ __launch_bounds__(256) void flash_attn_kernel(
    const bf16* __restrict__ Qb, const bf16* __restrict__ Kb,
    const bf16* __restrict__ Vb, bf16* __restrict__ O) {
    const int orig = blockIdx.x;
    const int xcd = orig & 7;           // hardware XCD round-robin
    const int idx = orig >> 3;          // 0..63 within XCD
    const int bh  = xcd * 4 + (idx >> 4);   // 4 (b,h) pairs per XCD
    const int qt  = idx & 15;           // S/128 = 16 q-tiles
    const int h  = bh & 15;
    const int b  = bh >> 4;
    const int q0 = qt * 128;
    const int tid = threadIdx.x;
    const int lane = tid & 63;
    const int wv = tid >> 6;            // 0..3
    const int half = lane >> 5;         // 0/1
    const int l31 = lane & 31;

    __shared__ short Ab[128 * FSTRIDE];     // Q staging
    __shared__ short Ks[2][64 * 64];        // async-staged, XOR-swizzled, dbuf
    __shared__ short Vt[2][64 * FSTRIDE];   // V^T, dbuf

    const size_t headOff = (size_t)h * D_HEAD;
    const float SCF = 0.18033688f;      // 0.125 * log2(e), folded into Q

    // Stage Q (128 rows x 64 shorts), scaled by SCF. 2 threads per row.
    {
        int r = tid >> 1, c0 = (tid & 1) * 32;
        const short* src = (const short*)Qb + (size_t)(b * SEQ + q0 + r) * QKV_N + headOff + c0;
#pragma unroll
        for (int ch = 0; ch < 4; ch++) {
            short8 v = *(const short8*)(src + ch * 8);
            short8 o;
#pragma unroll
            for (int e = 0; e < 8; e++)
                o[e] = (short)f2b(b2f((unsigned short)v[e]) * SCF);
            *(short8*)&Ab[r * FSTRIDE + c0 + ch * 8] = o;
        }
    }

    const int sRow = lane >> 3;             // 0..7
    const int gChunk = (lane & 7) ^ sRow;   // global chunk for swizzled slot
    const int vjp = (tid & 31) * 2;         // V: 2 j's per thread
    const int vd0 = (tid >> 5) * 8;         // V: 8 d's per thread

    // Prologue: prefetch tile 0 (K async -> Ks[0], V -> regs)
#pragma unroll
    for (int rd = 0; rd < 2; rd++) {
        const short* gp = (const short*)Kb +
            (size_t)(b * SEQ + rd * 32 + wv * 8 + sRow) * QKV_N + headOff + gChunk * 8;
        async16(gp, &Ks[0][(rd * 32 + wv * 8) * 64]);
    }
    short8 v0, v1;
    {
        const short* s0 = (const short*)Vb + (size_t)(b * SEQ + vjp) * QKV_N + headOff + vd0;
        v0 = *(const short8*)s0;
        v1 = *(const short8*)(s0 + QKV_N);
    }
    __syncthreads();   // Q visible; K(0) landed; V(0) regs ready

    short8 a_q[4];     // Q fragment (B-operand of swapped QK^T)
#pragma unroll
    for (int ks = 0; ks < 4; ks++)
        a_q[ks] = *(const short8*)&Ab[(wv * 32 + l31) * FSTRIDE + ks * 16 + half * 8];

    // Write V(0) -> Vt[0] via v_perm byte-merge
    {
        union { short8 s; unsigned int w[4]; } U0, U1;
        U0.s = v0; U1.s = v1;
#pragma unroll
        for (int w = 0; w < 4; w++) {
            unsigned int we = __builtin_amdgcn_perm(U1.w[w], U0.w[w], 0x05040100u);
            unsigned int wo = __builtin_amdgcn_perm(U1.w[w], U0.w[w], 0x07060302u);
            *(unsigned int*)&Vt[0][(vd0 + 2 * w) * FSTRIDE + vjp] = we;
            *(unsigned int*)&Vt[0][(vd0 + 2 * w + 1) * FSTRIDE + vjp] = wo;
        }
    }
    __syncthreads();   // Vt[0] visible

    short8 vone;       // bf16 1.0 x8 (B-operand for the l-sum MFMA)
#pragma unroll
    for (int e = 0; e < 8; e++) vone[e] = (short)0x3F80;
    float16v zconst;   // persistent zero C-in for first QK MFMA (no re-init)
#pragma unroll
    for (int i = 0; i < 16; i++) zconst[i] = 0.f;

    float16v o_acc[2], l_acc;
#pragma unroll
    for (int i = 0; i < 16; i++) { o_acc[0][i] = 0.f; o_acc[1][i] = 0.f; l_acc[i] = 0.f; }

    int cb = 0;
    for (int t = 0; t < SEQ / 64; t++) {
        // Prefetch tile t+1 (clamped to last tile: harmless re-stage, no OOB)
        const int jn = (t < SEQ / 64 - 1) ? (t + 1) * 64 : t * 64;
#pragma unroll
        for (int rd = 0; rd < 2; rd++) {
            const short* gp = (const short*)Kb +
                (size_t)(b * SEQ + jn + rd * 32 + wv * 8 + sRow) * QKV_N + headOff + gChunk * 8;
            async16(gp, &Ks[cb ^ 1][(rd * 32 + wv * 8) * 64]);
        }
        {
            const short* s0 = (const short*)Vb + (size_t)(b * SEQ + jn + vjp) * QKV_N + headOff + vd0;
            v0 = *(const short8*)s0;
            v1 = *(const short8*)(s0 + QKV_N);
        }

        // Swapped QK^T: A = K rows (j), B = Q rows (q). C: row=j, col=q=l31.
        // First ks uses zconst as C-in (no 32-mov zero-init).
        float16v s_acc[2];
        __builtin_amdgcn_s_setprio(1);
#pragma unroll
        for (int jb = 0; jb < 2; jb++) {
            const int row = jb * 32 + l31;
            const int slot = half ^ (l31 & 7);   // ks=0
            short8 kfr = *(const short8*)&Ks[cb][row * 64 + slot * 8];
            s_acc[jb] = __builtin_amdgcn_mfma_f32_32x32x16_bf16(kfr, a_q[0], zconst, 0, 0, 0);
        }
#pragma unroll
        for (int ks = 1; ks < 4; ks++)
#pragma unroll
            for (int jb = 0; jb < 2; jb++) {
                const int row = jb * 32 + l31;
                const int slot = (ks * 2 + half) ^ (l31 & 7);
                short8 kfr = *(const short8*)&Ks[cb][row * 64 + slot * 8];
                s_acc[jb] = __builtin_amdgcn_mfma_f32_32x32x16_bf16(kfr, a_q[ks], s_acc[jb], 0, 0, 0);
            }
        __builtin_amdgcn_s_setprio(0);

        // p = exp2(s) in-register
#pragma unroll
        for (int jb = 0; jb < 2; jb++)
#pragma unroll
            for (int reg = 0; reg < 16; reg++)
                s_acc[jb][reg] = exp2f(s_acc[jb][reg]);

        // T12: build PV A-fragments in-register (cvt_pk + permlane32_swap)
        short8 pa[4];
#pragma unroll
        for (int jb = 0; jb < 2; jb++)
#pragma unroll
            for (int c = 0; c < 2; c++) {
                unsigned int a0 = cvt_pk_bf16(s_acc[jb][8 * c + 0], s_acc[jb][8 * c + 1]);
                unsigned int a1 = cvt_pk_bf16(s_acc[jb][8 * c + 2], s_acc[jb][8 * c + 3]);
                unsigned int b0 = cvt_pk_bf16(s_acc[jb][8 * c + 4], s_acc[jb][8 * c + 5]);
                unsigned int b1 = cvt_pk_bf16(s_acc[jb][8 * c + 6], s_acc[jb][8 * c + 7]);
                pl32_swap(a0, b0);
                pl32_swap(a1, b1);
                union { unsigned int w[4]; short8 s; } u;
                u.w[0] = a0; u.w[1] = a1; u.w[2] = b0; u.w[3] = b1;
                pa[jb * 2 + c] = u.s;
            }

        // PV: A = pa (in regs), B = Vt[cb] (2 d-blocks x 4 k-chunks).
        // l_acc: denominator via mfma(pa, ones) on the MFMA pipe.
        __builtin_amdgcn_s_setprio(1);
#pragma unroll
        for (int ks = 0; ks < 4; ks++) {
#pragma unroll
            for (int db = 0; db < 2; db++) {
                short8 vbf = *(const short8*)&Vt[cb][(db * 32 + l31) * FSTRIDE + ks * 16 + half * 8];
                o_acc[db] = __builtin_amdgcn_mfma_f32_32x32x16_bf16(pa[ks], vbf, o_acc[db], 0, 0, 0);
            }
            l_acc = __builtin_amdgcn_mfma_f32_32x32x16_bf16(pa[ks], vone, l_acc, 0, 0, 0);
        }
        __builtin_amdgcn_s_setprio(0);

        // Write V(t+1) -> Vt[cb^1] after PV (R9/R11 placement): PV's
        // ds_reads stay ahead of these ds_writes on the LDS pipe.
        {
            union { short8 s; unsigned int w[4]; } U0, U1;
            U0.s = v0; U1.s = v1;
#pragma unroll
            for (int w = 0; w < 4; w++) {
                unsigned int we = __builtin_amdgcn_perm(U1.w[w], U0.w[w], 0x05040100u);
                unsigned int wo = __builtin_amdgcn_perm(U1.w[w], U0.w[w], 0x07060302u);
                *(unsigned int*)&Vt[cb ^ 1][(vd0 + 2 * w) * FSTRIDE + vjp] = we;
                *(unsigned int*)&Vt[cb ^ 1][(vd0 + 2 * w + 1) * FSTRIDE + vjp] = wo;
            }
        }

        __syncthreads();   // drains: K(t+1) in Ks[cb^1], Vt[cb^1] visible,
                           // all waves done reading Ks[cb]/Vt[cb]
        cb ^= 1;
    }

    // l_acc[reg] = l for q-row rowC (identical in every lane): no shuffles.
    unsigned short* Ou = (unsigned short*)O;
#pragma unroll
    for (int reg = 0; reg < 16; reg++) {
        const int rowC = (reg & 3) + 8 * (reg >> 2) + 4 * half;
        const float invl = 1.0f / l_acc[reg];
        const int rowg = b * SEQ + q0 + wv * 32 + rowC;
#pragma unroll
        for (int db = 0; db < 2; db++)
            Ou[(size_t)rowg * D_MODEL + headOff + db * 32 + l31] =
                f2b(o_acc[db][reg] * invl);
    }
}

// ---------------------------------------------------------------------------
// out = LayerNorm(X + R) * g + be — one block per row of 1024, vectorized x4.
// ---------------------------------------------------------------------------
template <bool OUT_F32>
__global__ __launch_bounds__(256) void add_ln_kernel(
    const void* __restrict__ X, const bf16* __restrict__ R,
    const void* __restrict__ g, const void* __restrict__ be,
    void* __restrict__ Y,
    const int* __restrict__ xFlagp, const int* __restrict__ wFlagp) {
    const int xf = *xFlagp;
    const int wf = *wFlagp;
    const int row = blockIdx.x;
    const size_t base = (size_t)row * D_MODEL;
    const int tid = threadIdx.x;
    const int i0 = tid * 4;
    __shared__ float red[256];
    float v[4];
    if (xf) {
        float4v xv = *(const float4v*)((const float*)X + base + i0);
        short4v rv = *(const short4v*)((const short*)R + base + i0);
#pragma unroll
        for (int i = 0; i < 4; i++) v[i] = xv[i] + b2f((unsigned short)rv[i]);
    } else {
        short4v xv = *(const short4v*)((const short*)X + base + i0);
        short4v rv = *(const short4v*)((const short*)R + base + i0);
#pragma unroll
        for (int i = 0; i < 4; i++) v[i] = b2f((unsigned short)xv[i]) + b2f((unsigned short)rv[i]);
    }
    float s = v[0] + v[1] + v[2] + v[3];
    red[tid] = s; __syncthreads();
    for (int s2 = 128; s2 > 0; s2 >>= 1) {
        if (tid < s2) red[tid] += red[tid + s2];
        __syncthreads();
    }
    float mu = red[0] * (1.0f / D_MODEL);
    __syncthreads();
    float s2v = 0.f;
#pragma unroll
    for (int i = 0; i < 4; i++) { float dd = v[i] - mu; s2v += dd * dd; }
    red[tid] = s2v; __syncthreads();
    for (int s2 = 128; s2 > 0; s2 >>= 1) {
        if (tid < s2) red[tid] += red[tid + s2];
        __syncthreads();
    }
    float rstd = rsqrtf(red[0] * (1.0f / D_MODEL) + EPS);
    float gv[4], bv[4];
    if (wf) {
        float4v gg = *(const float4v*)((const float*)g + i0);
        float4v bb = *(const float4v*)((const float*)be + i0);
#pragma unroll
        for (int i = 0; i < 4; i++) { gv[i] = gg[i]; bv[i] = bb[i]; }
    } else {
        short4v gg = *(const short4v*)((const short*)g + i0);
        short4v bb = *(const short4v*)((const short*)be + i0);
#pragma unroll
        for (int i = 0; i < 4; i++) { gv[i] = b2f((unsigned short)gg[i]); bv[i] = b2f((unsigned short)bb[i]); }
    }
    if (OUT_F32) {
        float4v o;
#pragma unroll
        for (int i = 0; i < 4; i++) o[i] = (v[i] - mu) * rstd * gv[i] + bv[i];
        *(float4v*)((float*)Y + base + i0) = o;
    } else {
        short4v o;
#pragma unroll
        for (int i = 0; i < 4; i++) o[i] = (short)f2b((v[i] - mu) * rstd * gv[i] + bv[i]);
        *(short4v*)((short*)Y + base + i0) = o;
    }
}

// ---------------------------------------------------------------------------
extern "C" void kernel_launch(void* const* d_in, const int* in_sizes, int n_in,
                              void* d_out, int out_size, void* d_ws, size_t ws_size,
                              hipStream_t stream) {
    const void* x  = d_in[0];
    const void* Wq = d_in[1];  const void* bq = d_in[2];
    const void* Wk = d_in[3];  const void* bk = d_in[4];
    const void* Wv = d_in[5];  const void* bv = d_in[6];
    const void* Wo = d_in[7];  const void* bo = d_in[8];
    const void* W1 = d_in[9];  const void* b1 = d_in[10];
    const void* W2 = d_in[11]; const void* b2 = d_in[12];
    const void* g1 = d_in[13]; const void* be1 = d_in[14];
    const void* g2 = d_in[15]; const void* be2 = d_in[16];

    char* ws = (char*)d_ws;
    const size_t MB = 1024 * 1024;
    // Proven R9-R12 choreography (48 MB core):
    bf16* xb     = (bf16*)(ws + 0 * MB);
    bf16* wqkvb  = (bf16*)(ws + 8 * MB);
    bf16* wob    = (bf16*)(ws + 14 * MB);
    bf16* qkv    = (bf16*)(ws + 16 * MB);
    bf16* concat = (bf16*)(ws + 40 * MB);
    bf16* w1b    = (bf16*)(ws + 0 * MB);
    bf16* proj   = (bf16*)(ws + 16 * MB);
    bf16* hb     = (bf16*)(ws + 8 * MB);
    bf16* ffn1   = (bf16*)(ws + 16 * MB);
    bf16* ffn2   = (bf16*)(ws + 0 * MB);
    const bool castW2 = (ws_size >= 56 * MB + 8);
    bf16* w2b    = (bf16*)(ws + 48 * MB);
    int*  flag   = (int*)(ws + (castW2 ? 56 * MB : 48 * MB));

    const int* fIn = flag;
    const int* fBf = flag + 1;

    dim3 blk(256);

    detect_kernel<<<dim3(1), blk, 0, stream>>>((const unsigned short*)x, flag);
    cast_bf16_kernel<<<dim3((M_TOK * D_MODEL / 8 + 255) / 256), blk, 0, stream>>>(x, xb, M_TOK * D_MODEL, fIn);
    cast3_bf16_kernel<<<dim3(3 * D_MODEL * D_MODEL / 8 / 256), blk, 0, stream>>>(Wq, Wk, Wv, wqkvb, fIn);
    if (castW2)
        cast_bf16_kernel<<<dim3((D_FF * D_MODEL / 8 + 255) / 256), blk, 0, stream>>>(W2, w2b, D_FF * D_MODEL, fIn);
    // Fused QKV projection: 128x128 tiles, 768 blocks, XCD-partitioned M
    gemm_mfma<4, 4, false, false, true><<<dim3((QKV_N / 128) * (M_TOK / 128)), blk, 0, stream>>>(
        xb, wqkvb, bq, bk, bv, 1024, 2048, qkv, QKV_N, D_MODEL, fIn);
    // Wo + W1 casts in one launch (xb dead now)
    cast2_bf16_kernel<<<dim3(5 * D_MODEL * D_MODEL / 8 / 256), blk, 0, stream>>>(Wo, W1, wob, w1b, fIn);
    // Flash attention v13: 512 blocks x 256 threads (R11-verified, 79.8 us)
    flash_attn_kernel<<<dim3(BATCH * NHEAD * (SEQ / 128)), dim3(256), 0, stream>>>(
        qkv, qkv + D_MODEL, qkv + 2 * D_MODEL, concat);
    // Output projection: 64x64 tiles, 1024 blocks, XCD-partitioned M
    // (R12 settled: 64^2 <2,2> + MSWZ is the saddle point for N=1024 GEMMs)
    gemm_mfma<2, 2, false, false, true><<<dim3((D_MODEL / 64) * (M_TOK / 64)), blk, 0, stream>>>(
        concat, wob, bo, bo, bo, D_MODEL, D_MODEL, proj, D_MODEL, D_MODEL, fIn);
    add_ln_kernel<false><<<dim3(M_TOK), blk, 0, stream>>>(x, proj, g1, be1, hb, fIn, fIn);
    // FFN1: 128x128 tiles, ReLU, non-swizzled (R10 config, best measured)
    gemm_mfma<4, 4, true, false, false><<<dim3(D_FF / 128, M_TOK / 128), blk, 0, stream>>>(
        hb, w1b, b1, b1, b1, D_FF, D_FF, ffn1, D_FF, D_MODEL, fIn);
    // FFN2: 64x64 tiles, 1024 blocks, XCD-partitioned M
    if (castW2)
        gemm_mfma<2, 2, false, false, true><<<dim3((D_MODEL / 64) * (M_TOK / 64)), blk, 0, stream>>>(
            ffn1, w2b, b2, b2, b2, D_MODEL, D_MODEL, ffn2, D_MODEL, D_FF, fIn);
    else
        gemm_mfma<2, 2, false, true, true><<<dim3((D_MODEL / 64) * (M_TOK / 64)), blk, 0, stream>>>(
            ffn1, W2, b2, b2, b2, D_MODEL, D_MODEL, ffn2, D_MODEL, D_FF, fIn);
    add_ln_kernel<true><<<dim3(M_TOK), blk, 0, stream>>>(hb, ffn2, g2, be2, d_out, fBf, fIn);
}